// Round 5
// baseline (707.921 us; speedup 1.0000x reference)
//
#include <hip/hip_runtime.h>

// Problem constants (z: [4, 64, 32, 32, 32] f32, embedding: [1024, 64] f32)
#define CH     64
#define KC     1024
#define SP     32768              // 32*32*32
#define NBATCH 4
#define NTOK   (NBATCH * SP)      // 131072

// d_out flat layout (all float32): z_q, loss, perplexity, indices, mean(dist)
#define OFF_ZQ   0
#define OFF_LOSS (NBATCH * CH * SP)      // 8388608
#define OFF_PERP (OFF_LOSS + 1)
#define OFF_IDX  (OFF_PERP + 1)          // 8388610
#define OFF_MEAN (OFF_IDX + NTOK)        // 8519682

// workspace layout (32-bit words)
// [0,1024)      int   hist
// [1024]        float sum_z2
// [1025]        float sum_e2
// [1026,1090)   float sum_zc[64]
// [1090,1154)   float sum_ec[64]
// [1154,2178)   float enorm[1024]

// Fused prep: blocks 0-3 embed_norms, block 4 embed_col_stats (+ zero the
// atomic targets sums[0]/sum_zc), blocks 5-8 zero hist.
__global__ __launch_bounds__(256) void prep(const float* __restrict__ e,
                                            int* __restrict__ hist,
                                            float* __restrict__ sums,
                                            float* __restrict__ sum_zc,
                                            float* __restrict__ sum_ec,
                                            float* __restrict__ enorm) {
    const int tid = threadIdx.x;
    const int bk = blockIdx.x;
    if (bk < 4) {
        int k = bk * 256 + tid;
        const float4* row = (const float4*)(e + (size_t)k * CH);
        float n = 0.f;
#pragma unroll
        for (int j = 0; j < CH / 4; ++j) {
            float4 v = row[j];
            n += v.x * v.x + v.y * v.y + v.z * v.z + v.w * v.w;
        }
        enorm[k] = n;
    } else if (bk == 4) {
        if (tid == 0) sums[0] = 0.f;
        if (tid < 64) sum_zc[tid] = 0.f;
        __shared__ float ls1[256];
        __shared__ float r2[4];
        int c = tid & 63;
        int strip = tid >> 6;
        float s1 = 0.f, s2 = 0.f;
        for (int k = strip * 256; k < strip * 256 + 256; ++k) {
            float v = e[k * CH + c];
            s1 += v;
            s2 = fmaf(v, v, s2);
        }
        ls1[tid] = s1;
        for (int off = 32; off; off >>= 1) s2 += __shfl_down(s2, off);
        if ((tid & 63) == 0) r2[tid >> 6] = s2;
        __syncthreads();
        if (strip == 0) sum_ec[c] = ls1[c] + ls1[64 + c] + ls1[128 + c] + ls1[192 + c];
        if (tid == 0) sums[1] = r2[0] + r2[1] + r2[2] + r2[3];
    } else {
        hist[(bk - 5) * 256 + tid] = 0;
    }
}

// main: lane = token, z[64] in VGPRs, wave-uniform e rows double-buffered in
// registers with one-code-ahead prefetch (explicit software pipeline).
// launch_bounds(256,2): 256-VGPR budget so zr + both e-buffers live in VGPRs
// (round 4's (256,4)=128-cap forced AGPR shuffling of zr -> 30% VALUBusy).
// Distance arithmetic is line-for-line identical to round 4 (passed, absmax 0).
// Also folds the z statistics (sum z^2, per-channel sum z) since zr is here.
__global__ __launch_bounds__(256, 2) void vq_main(const float* __restrict__ z,
                                                  const float* __restrict__ emb,
                                                  const float* __restrict__ enorm,
                                                  float* __restrict__ out,
                                                  int* __restrict__ hist,
                                                  float* __restrict__ sums,
                                                  float* __restrict__ sum_zc) {
    __shared__ int lh[KC];   // 4 KB block histogram

    const int tid = threadIdx.x;
    const int lane = tid & 63;
    const int t = blockIdx.x * 256 + tid;   // token id, grid = 512
    const int b = t >> 15;
    const int s = t & (SP - 1);

    for (int i = tid; i < KC; i += 256) lh[i] = 0;

    const float* zp = z + (size_t)b * (CH * SP) + s;
    float zr[CH];
#pragma unroll
    for (int c = 0; c < CH; ++c) zr[c] = zp[(size_t)c * SP];   // coalesced per c

    float bestv = 3.4e38f;
    int besti = 0;

    const float4* ep = (const float4*)emb;   // row k = ep[16k .. 16k+15]
    float4 e0[16], e1[16];
#pragma unroll
    for (int j = 0; j < 16; ++j) e0[j] = ep[j];   // prime: code 0

    for (int code = 0; code < KC; code += 2) {
        // prefetch code+1 into e1 (slack: the whole e0 FMA block below)
#pragma unroll
        for (int j = 0; j < 16; ++j) e1[j] = ep[(code + 1) * 16 + j];
        {
            float a0 = 0.f, a1 = 0.f, a2 = 0.f, a3 = 0.f;
#pragma unroll
            for (int j = 0; j < 16; ++j) {
                a0 = fmaf(zr[4 * j + 0], e0[j].x, a0);
                a1 = fmaf(zr[4 * j + 1], e0[j].y, a1);
                a2 = fmaf(zr[4 * j + 2], e0[j].z, a2);
                a3 = fmaf(zr[4 * j + 3], e0[j].w, a3);
            }
            float d = enorm[code] - 2.f * ((a0 + a1) + (a2 + a3));
            if (d < bestv) { bestv = d; besti = code; }
        }
        // prefetch code+2 into e0 (clamped reload of row 0 on last iter)
        {
            int nc = (code + 2 < KC) ? (code + 2) : 0;
#pragma unroll
            for (int j = 0; j < 16; ++j) e0[j] = ep[nc * 16 + j];
        }
        {
            float a0 = 0.f, a1 = 0.f, a2 = 0.f, a3 = 0.f;
#pragma unroll
            for (int j = 0; j < 16; ++j) {
                a0 = fmaf(zr[4 * j + 0], e1[j].x, a0);
                a1 = fmaf(zr[4 * j + 1], e1[j].y, a1);
                a2 = fmaf(zr[4 * j + 2], e1[j].z, a2);
                a3 = fmaf(zr[4 * j + 3], e1[j].w, a3);
            }
            float d = enorm[code + 1] - 2.f * ((a0 + a1) + (a2 + a3));
            if (d < bestv) { bestv = d; besti = code + 1; }
        }
    }

    // indices output (buffer is float32), coalesced
    out[OFF_IDX + t] = (float)besti;

    // histogram: LDS then one global atomic per nonzero bin
    atomicAdd(&lh[besti], 1);

    // ---- folded z statistics (order-insensitive outputs) ----
    {
        float s2 = 0.f;
#pragma unroll
        for (int c = 0; c < CH; ++c) s2 = fmaf(zr[c], zr[c], s2);
#pragma unroll
        for (int off = 32; off; off >>= 1) s2 += __shfl_xor(s2, off);
        float mych = 0.f;
#pragma unroll
        for (int c = 0; c < CH; ++c) {
            float v = zr[c];
#pragma unroll
            for (int off = 32; off; off >>= 1) v += __shfl_xor(v, off);
            if (lane == c) mych = v;   // lane c keeps channel c's wave-sum
        }
        atomicAdd(&sum_zc[lane], mych);          // 64 consecutive addresses
        if (lane == 0) atomicAdd(&sums[0], s2);
    }

    __syncthreads();
    for (int i = tid; i < KC; i += 256) {
        int v = lh[i];
        if (v) atomicAdd(&hist[i], v);
    }

    // z_q = z + (e[besti] - z): per-lane gather (L2-hot), coalesced writes
    const float4* eq = (const float4*)(emb + (size_t)besti * CH);
    float* oq = out + OFF_ZQ + (size_t)b * (CH * SP) + s;
#pragma unroll
    for (int j = 0; j < CH / 4; ++j) {
        float4 v = eq[j];
        int c = 4 * j;
        oq[(size_t)(c + 0) * SP] = zr[c + 0] + (v.x - zr[c + 0]);
        oq[(size_t)(c + 1) * SP] = zr[c + 1] + (v.y - zr[c + 1]);
        oq[(size_t)(c + 2) * SP] = zr[c + 2] + (v.z - zr[c + 2]);
        oq[(size_t)(c + 3) * SP] = zr[c + 3] + (v.w - zr[c + 3]);
    }
}

__global__ __launch_bounds__(1024) void finalize(const int* __restrict__ hist,
                                                 const float* __restrict__ sums,
                                                 const float* __restrict__ sum_zc,
                                                 const float* __restrict__ sum_ec,
                                                 float* __restrict__ out) {
    __shared__ float red[1024];
    int k = threadIdx.x;
    float p = (float)hist[k] * (1.0f / (float)NTOK);
    red[k] = p * logf(p + 1e-10f);
    __syncthreads();
    for (int off = 512; off; off >>= 1) {
        if (k < off) red[k] += red[k + off];
        __syncthreads();
    }
    if (k == 0) {
        out[OFF_PERP] = expf(-red[0]);
        out[OFF_LOSS] = 0.f;
        double dot = 0.0;
        for (int c = 0; c < CH; ++c) dot += (double)sum_zc[c] * (double)sum_ec[c];
        double mean = ((double)KC * (double)sums[0] + (double)NTOK * (double)sums[1] - 2.0 * dot)
                      / ((double)NTOK * (double)KC);
        out[OFF_MEAN] = (float)mean;
    }
}

extern "C" void kernel_launch(void* const* d_in, const int* in_sizes, int n_in,
                              void* d_out, int out_size, void* d_ws, size_t ws_size,
                              hipStream_t stream) {
    const float* z   = (const float*)d_in[0];
    const float* emb = (const float*)d_in[1];
    float* out = (float*)d_out;

    int*   hist   = (int*)d_ws;
    float* sums   = (float*)d_ws + 1024;   // [0]=sum_z2 [1]=sum_e2
    float* sum_zc = (float*)d_ws + 1026;
    float* sum_ec = (float*)d_ws + 1090;
    float* enorm  = (float*)d_ws + 1154;

    prep<<<9, 256, 0, stream>>>(emb, hist, sums, sum_zc, sum_ec, enorm);
    vq_main<<<NTOK / 256, 256, 0, stream>>>(z, emb, enorm, out, hist, sums, sum_zc);
    finalize<<<1, 1024, 0, stream>>>(hist, sums, sum_zc, sum_ec, out);
}

// Round 6
// 438.122 us; speedup vs baseline: 1.6158x; 1.6158x over previous
//
#include <hip/hip_runtime.h>

// Problem constants (z: [4, 64, 32, 32, 32] f32, embedding: [1024, 64] f32)
#define CH     64
#define KC     1024
#define SP     32768              // 32*32*32
#define NBATCH 4
#define NTOK   (NBATCH * SP)      // 131072
#define MTOK   128                // tokens per block
#define SZZ    68                 // zl row stride (floats): 272 B = 16B-aligned

// d_out flat layout (all float32): z_q, loss, perplexity, indices, mean(dist)
#define OFF_ZQ   0
#define OFF_LOSS (NBATCH * CH * SP)      // 8388608
#define OFF_PERP (OFF_LOSS + 1)
#define OFF_IDX  (OFF_PERP + 1)          // 8388610
#define OFF_MEAN (OFF_IDX + NTOK)        // 8519682

// workspace layout (32-bit words)
// [0,1024)      int   hist
// [1024]        float sum_z2
// [1025]        float sum_e2
// [1026,1090)   float sum_zc[64]
// [1090,1154)   float sum_ec[64]
// [1154,2178)   float enorm[1024]

// Fused prep: blocks 0-3 embed_norms, block 4 embed_col_stats (+ zero the
// atomic targets sums[0]/sum_zc), blocks 5-8 zero hist.
__global__ __launch_bounds__(256) void prep(const float* __restrict__ e,
                                            int* __restrict__ hist,
                                            float* __restrict__ sums,
                                            float* __restrict__ sum_zc,
                                            float* __restrict__ sum_ec,
                                            float* __restrict__ enorm) {
    const int tid = threadIdx.x;
    const int bk = blockIdx.x;
    if (bk < 4) {
        int k = bk * 256 + tid;
        const float4* row = (const float4*)(e + (size_t)k * CH);
        float n = 0.f;
#pragma unroll
        for (int j = 0; j < CH / 4; ++j) {
            float4 v = row[j];
            n += v.x * v.x + v.y * v.y + v.z * v.z + v.w * v.w;
        }
        enorm[k] = n;
    } else if (bk == 4) {
        if (tid == 0) sums[0] = 0.f;
        if (tid < 64) sum_zc[tid] = 0.f;
        __shared__ float ls1[256];
        __shared__ float r2[4];
        int c = tid & 63;
        int strip = tid >> 6;
        float s1 = 0.f, s2 = 0.f;
        for (int k = strip * 256; k < strip * 256 + 256; ++k) {
            float v = e[k * CH + c];
            s1 += v;
            s2 = fmaf(v, v, s2);
        }
        ls1[tid] = s1;
        for (int off = 32; off; off >>= 1) s2 += __shfl_down(s2, off);
        if ((tid & 63) == 0) r2[tid >> 6] = s2;
        __syncthreads();
        if (strip == 0) sum_ec[c] = ls1[c] + ls1[64 + c] + ls1[128 + c] + ls1[192 + c];
        if (tid == 0) sums[1] = r2[0] + r2[1] + r2[2] + r2[3];
    } else {
        hist[(bk - 5) * 256 + tid] = 0;
    }
}

// main: register-blocked distance GEMM. Block = 128 tokens x all 1024 codes.
// Thread tile: 8 tokens (tx+16i, tx=tid&15) x 4 codes (cb + u*16 + ty,
// ty=tid>>4). z staged once in LDS token-major (re-read per code-group);
// e read DIRECTLY from global (L1-resident 256 KB; each ef[u] address shared
// by 16 lanes -> broadcast). No barriers in the code loop. Halves the
// round-3 LDS instruction count (the measured wall).
// Distance arithmetic frozen bitwise from round 3 (absmax 0): float4
// stride-4 partial chains ascending jq, combine nrm - 2*((x+y)+(z+w)),
// codes enumerated ascending, strict <, cross-thread tie -> lower index.
__global__ __launch_bounds__(256, 2) void vq_main(const float* __restrict__ z,
                                                  const float* __restrict__ emb,
                                                  const float* __restrict__ enorm,
                                                  float* __restrict__ out,
                                                  int* __restrict__ hist,
                                                  float* __restrict__ sums,
                                                  float* __restrict__ sum_zc) {
    __shared__ float zl[MTOK * SZZ];   // 34816 B, token-major [t][c]
    __shared__ float rv[16 * MTOK];    // 8 KB (also z-stats scratch)
    __shared__ int   ri[16 * MTOK];    // 8 KB (also z-stats scratch)
    __shared__ int   fi[MTOK];
    __shared__ int   lh[KC];           // 4 KB

    const int tid = threadIdx.x;
    const int tx = tid & 15;
    const int ty = tid >> 4;            // 0..15
    const int t0 = blockIdx.x * MTOK;   // grid = 1024
    const int bb = t0 >> 15;
    const int s0 = t0 & (SP - 1);

    for (int i = tid; i < KC; i += 256) lh[i] = 0;

    // ---- stage z tile token-major: zl[t][c] = z[bb][c][s0+t] ----
    {
        const float* zbase = z + ((size_t)bb * CH) * SP + s0;
#pragma unroll
        for (int j = 0; j < 8; ++j) {
            int idx = tid + j * 256;        // 0..2047
            int c = idx >> 5;               // 0..63
            int tq = idx & 31;              // token quad
            float4 v = *(const float4*)(zbase + (size_t)c * SP + tq * 4);
            zl[(4 * tq + 0) * SZZ + c] = v.x;
            zl[(4 * tq + 1) * SZZ + c] = v.y;
            zl[(4 * tq + 2) * SZZ + c] = v.z;
            zl[(4 * tq + 3) * SZZ + c] = v.w;
        }
    }
    __syncthreads();

    // ---- folded z statistics (order only affects mean(dist); tol-insensitive) ----
    {
        int c = tid >> 2, q = tid & 3;
        float s1 = 0.f, s2 = 0.f;
        for (int tt = 0; tt < 32; ++tt) {
            float v = zl[(q * 32 + tt) * SZZ + c];
            s1 += v;
            s2 = fmaf(v, v, s2);
        }
        rv[tid] = s1;
        ((float*)ri)[tid] = s2;
    }
    __syncthreads();
    if (tid < 64) {   // wave 0 finalizes while others start the main loop
        float a = rv[4 * tid] + rv[4 * tid + 1] + rv[4 * tid + 2] + rv[4 * tid + 3];
        atomicAdd(&sum_zc[tid], a);
        const float* r2 = (const float*)ri;
        float b = r2[4 * tid] + r2[4 * tid + 1] + r2[4 * tid + 2] + r2[4 * tid + 3];
        for (int off = 32; off; off >>= 1) b += __shfl_down(b, off);
        if (tid == 0) atomicAdd(&sums[0], b);
    }

    // ---- main loop: no barriers, no LDS writes ----
    float bestv[8];
    int besti[8];
#pragma unroll
    for (int i = 0; i < 8; ++i) { bestv[i] = 3.4e38f; besti[i] = 0; }

    const float4* ep = (const float4*)emb;

    for (int cb = 0; cb < KC; cb += 64) {
        float en[4];
#pragma unroll
        for (int u = 0; u < 4; ++u) en[u] = enorm[cb + u * 16 + ty];

        float4 acc[8][4];
#pragma unroll
        for (int i = 0; i < 8; ++i)
#pragma unroll
            for (int u = 0; u < 4; ++u)
                acc[i][u] = make_float4(0.f, 0.f, 0.f, 0.f);

#pragma unroll 4
        for (int jq = 0; jq < 16; ++jq) {
            float4 ef[4];
#pragma unroll
            for (int u = 0; u < 4; ++u)
                ef[u] = ep[(size_t)(cb + u * 16 + ty) * 16 + jq];   // L1 broadcast
            float4 zk[8];
#pragma unroll
            for (int i = 0; i < 8; ++i)
                zk[i] = *(const float4*)&zl[(tx + 16 * i) * SZZ + 4 * jq];
#pragma unroll
            for (int i = 0; i < 8; ++i)
#pragma unroll
                for (int u = 0; u < 4; ++u) {
                    acc[i][u].x = fmaf(zk[i].x, ef[u].x, acc[i][u].x);
                    acc[i][u].y = fmaf(zk[i].y, ef[u].y, acc[i][u].y);
                    acc[i][u].z = fmaf(zk[i].z, ef[u].z, acc[i][u].z);
                    acc[i][u].w = fmaf(zk[i].w, ef[u].w, acc[i][u].w);
                }
        }

#pragma unroll
        for (int u = 0; u < 4; ++u) {
            float nrm = en[u];
            int code = cb + u * 16 + ty;
#pragma unroll
            for (int i = 0; i < 8; ++i) {
                // EXACT round-3 expression tree
                float d = nrm - 2.f * ((acc[i][u].x + acc[i][u].y) +
                                       (acc[i][u].z + acc[i][u].w));
                if (d < bestv[i]) { bestv[i] = d; besti[i] = code; }
            }
        }
    }

    __syncthreads();  // z-stats scratch reads done -> safe to overwrite rv/ri

    // ---- cross-thread argmin over the 16 ty's sharing a token ----
#pragma unroll
    for (int i = 0; i < 8; ++i) {
        int t = tx + 16 * i;
        rv[ty * MTOK + t] = bestv[i];
        ri[ty * MTOK + t] = besti[i];
    }
    __syncthreads();

    if (tid < MTOK) {
        float bv = rv[tid];
        int bi = ri[tid];
#pragma unroll
        for (int y = 1; y < 16; ++y) {
            float v = rv[y * MTOK + tid];
            int id = ri[y * MTOK + tid];
            if (v < bv || (v == bv && id < bi)) { bv = v; bi = id; }
        }
        fi[tid] = bi;
        out[OFF_IDX + t0 + tid] = (float)bi;    // coalesced
        atomicAdd(&lh[bi], 1);
    }
    __syncthreads();

    for (int i = tid; i < KC; i += 256) {
        int v = lh[i];
        if (v) atomicAdd(&hist[i], v);
    }

    // ---- z_q epilogue: z + (e[code] - z), coalesced per channel ----
#pragma unroll
    for (int j = 0; j < 32; ++j) {
        int idx = tid + j * 256;   // 0..8191
        int c = idx >> 7;
        int t = idx & 127;
        int code = fi[t];
        float ev = emb[(size_t)code * CH + c];   // L1/L2-hot gather
        float zv = zl[t * SZZ + c];
        out[OFF_ZQ + ((size_t)bb * CH + c) * SP + s0 + t] = zv + (ev - zv);
    }
}

__global__ __launch_bounds__(1024) void finalize(const int* __restrict__ hist,
                                                 const float* __restrict__ sums,
                                                 const float* __restrict__ sum_zc,
                                                 const float* __restrict__ sum_ec,
                                                 float* __restrict__ out) {
    __shared__ float red[1024];
    int k = threadIdx.x;
    float p = (float)hist[k] * (1.0f / (float)NTOK);
    red[k] = p * logf(p + 1e-10f);
    __syncthreads();
    for (int off = 512; off; off >>= 1) {
        if (k < off) red[k] += red[k + off];
        __syncthreads();
    }
    if (k == 0) {
        out[OFF_PERP] = expf(-red[0]);
        out[OFF_LOSS] = 0.f;
        double dot = 0.0;
        for (int c = 0; c < CH; ++c) dot += (double)sum_zc[c] * (double)sum_ec[c];
        double mean = ((double)KC * (double)sums[0] + (double)NTOK * (double)sums[1] - 2.0 * dot)
                      / ((double)NTOK * (double)KC);
        out[OFF_MEAN] = (float)mean;
    }
}

extern "C" void kernel_launch(void* const* d_in, const int* in_sizes, int n_in,
                              void* d_out, int out_size, void* d_ws, size_t ws_size,
                              hipStream_t stream) {
    const float* z   = (const float*)d_in[0];
    const float* emb = (const float*)d_in[1];
    float* out = (float*)d_out;

    int*   hist   = (int*)d_ws;
    float* sums   = (float*)d_ws + 1024;   // [0]=sum_z2 [1]=sum_e2
    float* sum_zc = (float*)d_ws + 1026;
    float* sum_ec = (float*)d_ws + 1090;
    float* enorm  = (float*)d_ws + 1154;

    prep<<<9, 256, 0, stream>>>(emb, hist, sums, sum_zc, sum_ec, enorm);
    vq_main<<<NTOK / MTOK, 256, 0, stream>>>(z, emb, enorm, out, hist, sums, sum_zc);
    finalize<<<1, 1024, 0, stream>>>(hist, sums, sum_zc, sum_ec, out);
}

// Round 7
// 369.684 us; speedup vs baseline: 1.9149x; 1.1851x over previous
//
#include <hip/hip_runtime.h>

// Problem constants (z: [4, 64, 32, 32, 32] f32, embedding: [1024, 64] f32)
#define CH     64
#define KC     1024
#define SP     32768              // 32*32*32
#define NBATCH 4
#define NTOK   (NBATCH * SP)      // 131072
#define MTOK   64                 // tokens per block
#define SZZ    68                 // zl row stride (floats)
#define CAP    16                 // candidate slots per token
#define MARGIN 3.0f               // > 2*eps, eps = max |d_bf16 - d_fp32| (~0.9)

// d_out flat layout (all float32): z_q, loss, perplexity, indices, mean(dist)
#define OFF_ZQ   0
#define OFF_LOSS (NBATCH * CH * SP)      // 8388608
#define OFF_PERP (OFF_LOSS + 1)
#define OFF_IDX  (OFF_PERP + 1)          // 8388610
#define OFF_MEAN (OFF_IDX + NTOK)        // 8519682

// workspace layout (32-bit words)
// [0,1024)      int   hist
// [1024]        float sum_z2
// [1025]        float sum_e2
// [1026,1090)   float sum_zc[64]
// [1090,1154)   float sum_ec[64]
// [1154,2178)   float enorm[1024]
// [4096,20480)  ushort eb[1024*64]  (bf16 embedding table, 128 KB)

typedef __attribute__((ext_vector_type(8))) short  s16x8;   // 8 bf16 (4 VGPRs)
typedef __attribute__((ext_vector_type(4))) float  f32x4;

__device__ __forceinline__ unsigned short f2bf(float f) {   // RNE, deterministic
    unsigned int u = __float_as_uint(f);
    return (unsigned short)((u + 0x7fffu + ((u >> 16) & 1u)) >> 16);
}

// frozen exact fp32 distance (bitwise identical to rounds 1/3/4: stride-4
// fmaf chains ascending j, combine nrm - 2*((a0+a1)+(a2+a3)))
__device__ __forceinline__ float exact_dist(const float* zrow,
                                            const float* __restrict__ emb,
                                            const float* enl, int c) {
    const float4* er = (const float4*)(emb + (size_t)c * CH);
    float a0 = 0.f, a1 = 0.f, a2 = 0.f, a3 = 0.f;
#pragma unroll
    for (int j = 0; j < 16; ++j) {
        float4 e4 = er[j];
        a0 = fmaf(zrow[4 * j + 0], e4.x, a0);
        a1 = fmaf(zrow[4 * j + 1], e4.y, a1);
        a2 = fmaf(zrow[4 * j + 2], e4.z, a2);
        a3 = fmaf(zrow[4 * j + 3], e4.w, a3);
    }
    return enl[c] - 2.f * ((a0 + a1) + (a2 + a3));
}

// prep: blocks 0-3 enorm, block 4 col-stats + zero sums, 5-8 zero hist,
// 9-12 fp32->bf16 embedding table.
__global__ __launch_bounds__(256) void prep(const float* __restrict__ e,
                                            int* __restrict__ hist,
                                            float* __restrict__ sums,
                                            float* __restrict__ sum_zc,
                                            float* __restrict__ sum_ec,
                                            float* __restrict__ enorm,
                                            unsigned short* __restrict__ eb) {
    const int tid = threadIdx.x;
    const int bk = blockIdx.x;
    if (bk < 4) {
        int k = bk * 256 + tid;
        const float4* row = (const float4*)(e + (size_t)k * CH);
        float n = 0.f;
#pragma unroll
        for (int j = 0; j < CH / 4; ++j) {
            float4 v = row[j];
            n += v.x * v.x + v.y * v.y + v.z * v.z + v.w * v.w;
        }
        enorm[k] = n;
    } else if (bk == 4) {
        if (tid == 0) sums[0] = 0.f;
        if (tid < 64) sum_zc[tid] = 0.f;
        __shared__ float ls1[256];
        __shared__ float r2[4];
        int c = tid & 63;
        int strip = tid >> 6;
        float s1 = 0.f, s2 = 0.f;
        for (int k = strip * 256; k < strip * 256 + 256; ++k) {
            float v = e[k * CH + c];
            s1 += v;
            s2 = fmaf(v, v, s2);
        }
        ls1[tid] = s1;
        for (int off = 32; off; off >>= 1) s2 += __shfl_down(s2, off);
        if ((tid & 63) == 0) r2[tid >> 6] = s2;
        __syncthreads();
        if (strip == 0) sum_ec[c] = ls1[c] + ls1[64 + c] + ls1[128 + c] + ls1[192 + c];
        if (tid == 0) sums[1] = r2[0] + r2[1] + r2[2] + r2[3];
    } else if (bk < 9) {
        hist[(bk - 5) * 256 + tid] = 0;
    } else {
        int base = (bk - 9) * 16384;
        for (int j = 0; j < 64; ++j) {
            int i = base + tid + j * 256;
            eb[i] = f2bf(e[i]);
        }
    }
}

// main: bf16-MFMA candidate generation + exact fp32 rescore.
// Block = 64 tokens (4 waves; wave w owns tokens w*16..w*16+15), all 1024
// codes as 64 16x16 tiles, K=64 as 2x mfma_f32_16x16x32_bf16.
// A-frag: lane holds z[m=w*16+(lane&15)][k=(lane>>4)*8+j]  (built once).
// B-frag: lane holds e[n=cb+(lane&15)][k=(lane>>4)*8+j]    (global bf16 table).
// D:      lane reg r = dist-dot for token w*16+4*(lane>>4)+r, code cb+(lane&15).
// Pass 1: per-token min of d_bf (value only). Pass 2 (identical compute):
// collect codes with d_bf <= min+MARGIN. Rescore those exactly in fp32.
__global__ __launch_bounds__(256, 4) void vq_main(const float* __restrict__ z,
                                                  const float* __restrict__ emb,
                                                  const unsigned short* __restrict__ eb,
                                                  const float* __restrict__ enorm,
                                                  float* __restrict__ out,
                                                  int* __restrict__ hist,
                                                  float* __restrict__ sums,
                                                  float* __restrict__ sum_zc) {
    __shared__ float zl[MTOK * SZZ];     // 17408 B fp32 z, token-major
    __shared__ float enorm_l[KC];        // 4096 B
    __shared__ float dmin_l[MTOK];       // 256 B
    __shared__ float zs1[256], zs2[256]; // 2048 B z-stats scratch
    __shared__ int   cand[MTOK][CAP];    // 4096 B
    __shared__ int   ccnt[MTOK];         // 256 B
    __shared__ int   fi[MTOK];           // 256 B

    const int tid = threadIdx.x;
    const int lane = tid & 63;
    const int w = tid >> 6;             // wave 0..3
    const int n15 = lane & 15;
    const int q = lane >> 4;            // 0..3
    const int t0 = blockIdx.x * MTOK;   // grid = 2048
    const int bb = t0 >> 15;
    const int s0 = t0 & (SP - 1);

    // ---- stage z tile token-major + enorm + ccnt ----
    {
        const float* zbase = z + ((size_t)bb * CH) * SP + s0;
#pragma unroll
        for (int j = 0; j < 4; ++j) {
            int idx = tid + j * 256;        // 0..1023
            int c = idx >> 4;
            int tq = idx & 15;
            float4 v = *(const float4*)(zbase + (size_t)c * SP + tq * 4);
            zl[(4 * tq + 0) * SZZ + c] = v.x;
            zl[(4 * tq + 1) * SZZ + c] = v.y;
            zl[(4 * tq + 2) * SZZ + c] = v.z;
            zl[(4 * tq + 3) * SZZ + c] = v.w;
        }
#pragma unroll
        for (int j = 0; j < 4; ++j) enorm_l[tid + j * 256] = enorm[tid + j * 256];
        if (tid < MTOK) ccnt[tid] = 0;
    }
    __syncthreads();

    // ---- folded z statistics (only affects mean(dist); tolerance-insensitive) ----
    {
        int c = tid >> 2, qq = tid & 3;
        float s1 = 0.f, s2 = 0.f;
        for (int tt = 0; tt < 16; ++tt) {
            float v = zl[(qq * 16 + tt) * SZZ + c];
            s1 += v;
            s2 = fmaf(v, v, s2);
        }
        zs1[tid] = s1;
        zs2[tid] = s2;
    }
    __syncthreads();
    if (tid < 64) {   // wave 0 finalizes; zs arrays never touched again
        float a = zs1[4 * tid] + zs1[4 * tid + 1] + zs1[4 * tid + 2] + zs1[4 * tid + 3];
        atomicAdd(&sum_zc[tid], a);
        float bsum = zs2[4 * tid] + zs2[4 * tid + 1] + zs2[4 * tid + 2] + zs2[4 * tid + 3];
        for (int off = 32; off; off >>= 1) bsum += __shfl_down(bsum, off);
        if (tid == 0) atomicAdd(&sums[0], bsum);
    }

    // ---- build persistent A fragments (tokens w*16 + n15, both k-halves) ----
    s16x8 A0, A1;
    {
        const float* zrow = &zl[(w * 16 + n15) * SZZ];
        float4 za = *(const float4*)(zrow + q * 8);
        float4 zb = *(const float4*)(zrow + q * 8 + 4);
        float4 zc = *(const float4*)(zrow + 32 + q * 8);
        float4 zd = *(const float4*)(zrow + 32 + q * 8 + 4);
        A0[0] = (short)f2bf(za.x); A0[1] = (short)f2bf(za.y);
        A0[2] = (short)f2bf(za.z); A0[3] = (short)f2bf(za.w);
        A0[4] = (short)f2bf(zb.x); A0[5] = (short)f2bf(zb.y);
        A0[6] = (short)f2bf(zb.z); A0[7] = (short)f2bf(zb.w);
        A1[0] = (short)f2bf(zc.x); A1[1] = (short)f2bf(zc.y);
        A1[2] = (short)f2bf(zc.z); A1[3] = (short)f2bf(zc.w);
        A1[4] = (short)f2bf(zd.x); A1[5] = (short)f2bf(zd.y);
        A1[6] = (short)f2bf(zd.z); A1[7] = (short)f2bf(zd.w);
    }
    const unsigned short* ebq = eb + (size_t)n15 * CH + q * 8;

    // ---- pass 1: per-token min of d_bf (values only) ----
    float bmin[4] = {3.4e38f, 3.4e38f, 3.4e38f, 3.4e38f};
    for (int ct = 0; ct < 64; ++ct) {
        int cb = ct * 16;
        const unsigned short* p = ebq + (size_t)cb * CH;
        s16x8 B0 = *(const s16x8*)p;
        s16x8 B1 = *(const s16x8*)(p + 32);
        f32x4 acc = {0.f, 0.f, 0.f, 0.f};
        acc = __builtin_amdgcn_mfma_f32_16x16x32_bf16(A0, B0, acc, 0, 0, 0);
        acc = __builtin_amdgcn_mfma_f32_16x16x32_bf16(A1, B1, acc, 0, 0, 0);
        float en = enorm_l[cb + n15];
#pragma unroll
        for (int r = 0; r < 4; ++r) {
            float d = fmaf(-2.f, acc[r], en);
            bmin[r] = fminf(bmin[r], d);
        }
    }
#pragma unroll
    for (int off = 1; off < 16; off <<= 1)
#pragma unroll
        for (int r = 0; r < 4; ++r)
            bmin[r] = fminf(bmin[r], __shfl_xor(bmin[r], off));
    if (n15 == 0)
#pragma unroll
        for (int r = 0; r < 4; ++r) dmin_l[w * 16 + 4 * q + r] = bmin[r];
    __syncthreads();

    // ---- pass 2: identical compute, collect candidates within margin ----
    float thr[4];
#pragma unroll
    for (int r = 0; r < 4; ++r) thr[r] = dmin_l[w * 16 + 4 * q + r] + MARGIN;
    for (int ct = 0; ct < 64; ++ct) {
        int cb = ct * 16;
        const unsigned short* p = ebq + (size_t)cb * CH;
        s16x8 B0 = *(const s16x8*)p;
        s16x8 B1 = *(const s16x8*)(p + 32);
        f32x4 acc = {0.f, 0.f, 0.f, 0.f};
        acc = __builtin_amdgcn_mfma_f32_16x16x32_bf16(A0, B0, acc, 0, 0, 0);
        acc = __builtin_amdgcn_mfma_f32_16x16x32_bf16(A1, B1, acc, 0, 0, 0);
        float en = enorm_l[cb + n15];
#pragma unroll
        for (int r = 0; r < 4; ++r) {
            float d = fmaf(-2.f, acc[r], en);
            if (d <= thr[r]) {
                int t = w * 16 + 4 * q + r;
                int pos = atomicAdd(&ccnt[t], 1);
                if (pos < CAP) cand[t][pos] = cb + n15;
            }
        }
    }
    __syncthreads();

    // ---- exact fp32 rescore of candidates (frozen arithmetic) ----
    if (tid < MTOK) {
        int t = tid;
        const float* zrow = &zl[t * SZZ];
        int cnt = ccnt[t];
        float best = 3.4e38f;
        int bi = 0;
        if (cnt <= CAP) {
            for (int j = 0; j < cnt; ++j) {
                int c = cand[t][j];
                float d = exact_dist(zrow, emb, enorm_l, c);
                if (d < best || (d == best && c < bi)) { best = d; bi = c; }
            }
        } else {   // overflow fallback (provably ~never): exact scan, ascending
            for (int c = 0; c < KC; ++c) {
                float d = exact_dist(zrow, emb, enorm_l, c);
                if (d < best) { best = d; bi = c; }
            }
        }
        fi[t] = bi;
        out[OFF_IDX + t0 + t] = (float)bi;   // coalesced
        atomicAdd(&hist[bi], 1);
    }
    __syncthreads();

    // ---- z_q epilogue: z + (e[code] - z), coalesced per channel ----
#pragma unroll
    for (int j = 0; j < 16; ++j) {
        int idx = tid + j * 256;   // 0..4095
        int c = idx >> 6;
        int t = idx & 63;
        int code = fi[t];
        float ev = emb[(size_t)code * CH + c];   // L1/L2-hot gather
        float zv = zl[t * SZZ + c];
        out[OFF_ZQ + ((size_t)bb * CH + c) * SP + s0 + t] = zv + (ev - zv);
    }
}

__global__ __launch_bounds__(1024) void finalize(const int* __restrict__ hist,
                                                 const float* __restrict__ sums,
                                                 const float* __restrict__ sum_zc,
                                                 const float* __restrict__ sum_ec,
                                                 float* __restrict__ out) {
    __shared__ float red[1024];
    int k = threadIdx.x;
    float p = (float)hist[k] * (1.0f / (float)NTOK);
    red[k] = p * logf(p + 1e-10f);
    __syncthreads();
    for (int off = 512; off; off >>= 1) {
        if (k < off) red[k] += red[k + off];
        __syncthreads();
    }
    if (k == 0) {
        out[OFF_PERP] = expf(-red[0]);
        out[OFF_LOSS] = 0.f;
        double dot = 0.0;
        for (int c = 0; c < CH; ++c) dot += (double)sum_zc[c] * (double)sum_ec[c];
        double mean = ((double)KC * (double)sums[0] + (double)NTOK * (double)sums[1] - 2.0 * dot)
                      / ((double)NTOK * (double)KC);
        out[OFF_MEAN] = (float)mean;
    }
}

extern "C" void kernel_launch(void* const* d_in, const int* in_sizes, int n_in,
                              void* d_out, int out_size, void* d_ws, size_t ws_size,
                              hipStream_t stream) {
    const float* z   = (const float*)d_in[0];
    const float* emb = (const float*)d_in[1];
    float* out = (float*)d_out;

    int*            hist   = (int*)d_ws;
    float*          sums   = (float*)d_ws + 1024;   // [0]=sum_z2 [1]=sum_e2
    float*          sum_zc = (float*)d_ws + 1026;
    float*          sum_ec = (float*)d_ws + 1090;
    float*          enorm  = (float*)d_ws + 1154;
    unsigned short* eb     = (unsigned short*)((int*)d_ws + 4096);  // 128 KB bf16 table

    prep<<<13, 256, 0, stream>>>(emb, hist, sums, sum_zc, sum_ec, enorm, eb);
    vq_main<<<NTOK / MTOK, 256, 0, stream>>>(z, emb, eb, enorm, out, hist, sums, sum_zc);
    finalize<<<1, 1024, 0, stream>>>(hist, sums, sum_zc, sum_ec, out);
}

// Round 8
// 227.725 us; speedup vs baseline: 3.1087x; 1.6234x over previous
//
#include <hip/hip_runtime.h>

// Problem constants (z: [4, 64, 32, 32, 32] f32, embedding: [1024, 64] f32)
#define CH     64
#define KC     1024
#define SP     32768              // 32*32*32
#define NBATCH 4
#define NTOK   (NBATCH * SP)      // 131072
#define MTOK   64                 // tokens per block
#define SZZ    68                 // zl row stride (floats)
#define ECH    256                // codes per LDS chunk
#define SZEB   72                 // ebl row stride in shorts (144 B = 9*16, b128-aligned)
#define CAP    16                 // candidate slots per token
#define MARGIN 3.0f               // > 2*eps, eps = max |d_bf16 - d_fp32| (~0.9)

// d_out flat layout (all float32): z_q, loss, perplexity, indices, mean(dist)
#define OFF_ZQ   0
#define OFF_LOSS (NBATCH * CH * SP)      // 8388608
#define OFF_PERP (OFF_LOSS + 1)
#define OFF_IDX  (OFF_PERP + 1)          // 8388610
#define OFF_MEAN (OFF_IDX + NTOK)        // 8519682

// workspace layout (32-bit words)
// [0,1024)      int   hist
// [1024]        float sum_z2
// [1025]        float sum_e2
// [1026,1090)   float sum_zc[64]
// [1090,1154)   float sum_ec[64]
// [1154,2178)   float enorm[1024]
// [4096,20480)  ushort eb[1024*64]  (bf16 embedding table, 128 KB)

typedef __attribute__((ext_vector_type(8))) short  s16x8;   // 8 bf16 (4 VGPRs)
typedef __attribute__((ext_vector_type(4))) float  f32x4;

__device__ __forceinline__ unsigned short f2bf(float f) {   // RNE, deterministic
    unsigned int u = __float_as_uint(f);
    return (unsigned short)((u + 0x7fffu + ((u >> 16) & 1u)) >> 16);
}

// frozen exact fp32 distance (bitwise identical to rounds 1/3/4/7: stride-4
// fmaf chains ascending j, combine nrm - 2*((a0+a1)+(a2+a3)))
__device__ __forceinline__ float exact_dist(const float* zrow,
                                            const float* __restrict__ emb,
                                            const float* enl, int c) {
    const float4* er = (const float4*)(emb + (size_t)c * CH);
    float a0 = 0.f, a1 = 0.f, a2 = 0.f, a3 = 0.f;
#pragma unroll
    for (int j = 0; j < 16; ++j) {
        float4 e4 = er[j];
        a0 = fmaf(zrow[4 * j + 0], e4.x, a0);
        a1 = fmaf(zrow[4 * j + 1], e4.y, a1);
        a2 = fmaf(zrow[4 * j + 2], e4.z, a2);
        a3 = fmaf(zrow[4 * j + 3], e4.w, a3);
    }
    return enl[c] - 2.f * ((a0 + a1) + (a2 + a3));
}

// prep: blocks 0-3 enorm, block 4 col-stats + zero sums, 5-8 zero hist,
// 9-12 fp32->bf16 embedding table.
__global__ __launch_bounds__(256) void prep(const float* __restrict__ e,
                                            int* __restrict__ hist,
                                            float* __restrict__ sums,
                                            float* __restrict__ sum_zc,
                                            float* __restrict__ sum_ec,
                                            float* __restrict__ enorm,
                                            unsigned short* __restrict__ eb) {
    const int tid = threadIdx.x;
    const int bk = blockIdx.x;
    if (bk < 4) {
        int k = bk * 256 + tid;
        const float4* row = (const float4*)(e + (size_t)k * CH);
        float n = 0.f;
#pragma unroll
        for (int j = 0; j < CH / 4; ++j) {
            float4 v = row[j];
            n += v.x * v.x + v.y * v.y + v.z * v.z + v.w * v.w;
        }
        enorm[k] = n;
    } else if (bk == 4) {
        if (tid == 0) sums[0] = 0.f;
        if (tid < 64) sum_zc[tid] = 0.f;
        __shared__ float ls1[256];
        __shared__ float r2[4];
        int c = tid & 63;
        int strip = tid >> 6;
        float s1 = 0.f, s2 = 0.f;
        for (int k = strip * 256; k < strip * 256 + 256; ++k) {
            float v = e[k * CH + c];
            s1 += v;
            s2 = fmaf(v, v, s2);
        }
        ls1[tid] = s1;
        for (int off = 32; off; off >>= 1) s2 += __shfl_down(s2, off);
        if ((tid & 63) == 0) r2[tid >> 6] = s2;
        __syncthreads();
        if (strip == 0) sum_ec[c] = ls1[c] + ls1[64 + c] + ls1[128 + c] + ls1[192 + c];
        if (tid == 0) sums[1] = r2[0] + r2[1] + r2[2] + r2[3];
    } else if (bk < 9) {
        hist[(bk - 5) * 256 + tid] = 0;
    } else {
        int base = (bk - 9) * 16384;
        for (int j = 0; j < 64; ++j) {
            int i = base + tid + j * 256;
            eb[i] = f2bf(e[i]);
        }
    }
}

// main: bf16-MFMA candidate generation (B-fragments from LDS-staged chunks)
// + exact fp32 rescore. Decision logic identical to round 7 (absmax 0).
__global__ __launch_bounds__(256, 2) void vq_main(const float* __restrict__ z,
                                                  const float* __restrict__ emb,
                                                  const unsigned short* __restrict__ eb,
                                                  const float* __restrict__ enorm,
                                                  float* __restrict__ out,
                                                  int* __restrict__ hist,
                                                  float* __restrict__ sums,
                                                  float* __restrict__ sum_zc) {
    __shared__ float zl[MTOK * SZZ];          // 17408 B fp32 z, token-major
    __shared__ unsigned short ebl[ECH * SZEB];// 36864 B bf16 e chunk, padded rows
    __shared__ float enorm_l[KC];             // 4096 B
    __shared__ float dmin_l[MTOK];            // 256 B
    __shared__ float zs1[256], zs2[256];      // 2048 B z-stats scratch
    __shared__ int   cand[MTOK][CAP];         // 4096 B
    __shared__ int   ccnt[MTOK];              // 256 B
    __shared__ int   fi[MTOK];                // 256 B

    const int tid = threadIdx.x;
    const int w = tid >> 6;             // wave 0..3
    const int lane = tid & 63;
    const int n15 = lane & 15;
    const int q = lane >> 4;            // 0..3
    const int t0 = blockIdx.x * MTOK;   // grid = 2048
    const int bb = t0 >> 15;
    const int s0 = t0 & (SP - 1);

    // ---- stage z tile token-major + enorm + ccnt ----
    {
        const float* zbase = z + ((size_t)bb * CH) * SP + s0;
#pragma unroll
        for (int j = 0; j < 4; ++j) {
            int idx = tid + j * 256;        // 0..1023
            int c = idx >> 4;
            int tq = idx & 15;
            float4 v = *(const float4*)(zbase + (size_t)c * SP + tq * 4);
            zl[(4 * tq + 0) * SZZ + c] = v.x;
            zl[(4 * tq + 1) * SZZ + c] = v.y;
            zl[(4 * tq + 2) * SZZ + c] = v.z;
            zl[(4 * tq + 3) * SZZ + c] = v.w;
        }
#pragma unroll
        for (int j = 0; j < 4; ++j) enorm_l[tid + j * 256] = enorm[tid + j * 256];
        if (tid < MTOK) ccnt[tid] = 0;
    }
    __syncthreads();

    // ---- build persistent A fragments (round-7 layout, verified) ----
    s16x8 A0, A1;
    {
        const float* zrow = &zl[(w * 16 + n15) * SZZ];
        float4 za = *(const float4*)(zrow + q * 8);
        float4 zb = *(const float4*)(zrow + q * 8 + 4);
        float4 zc = *(const float4*)(zrow + 32 + q * 8);
        float4 zd = *(const float4*)(zrow + 32 + q * 8 + 4);
        A0[0] = (short)f2bf(za.x); A0[1] = (short)f2bf(za.y);
        A0[2] = (short)f2bf(za.z); A0[3] = (short)f2bf(za.w);
        A0[4] = (short)f2bf(zb.x); A0[5] = (short)f2bf(zb.y);
        A0[6] = (short)f2bf(zb.z); A0[7] = (short)f2bf(zb.w);
        A1[0] = (short)f2bf(zc.x); A1[1] = (short)f2bf(zc.y);
        A1[2] = (short)f2bf(zc.z); A1[3] = (short)f2bf(zc.w);
        A1[4] = (short)f2bf(zd.x); A1[5] = (short)f2bf(zd.y);
        A1[6] = (short)f2bf(zd.z); A1[7] = (short)f2bf(zd.w);
    }
    const unsigned short* ebq = ebl + (size_t)n15 * SZEB + q * 8;

    // ---- pass 1: per-token min of d_bf (values only), chunked B in LDS ----
    float bmin[4] = {3.4e38f, 3.4e38f, 3.4e38f, 3.4e38f};
    for (int ch = 0; ch < 4; ++ch) {
        __syncthreads();   // prior chunk's ebl reads done
        // stage chunk ch: row = i>>3 (fully coalesced 128-B rows), j = i&7
#pragma unroll
        for (int rep = 0; rep < 8; ++rep) {
            int i = tid + rep * 256;         // 0..2047
            int row = i >> 3, j = i & 7;
            ((float4*)&ebl[row * SZEB])[j] =
                ((const float4*)(eb + (size_t)(ch * ECH + row) * CH))[j];
        }
        __syncthreads();
        for (int ct = 0; ct < 16; ++ct) {
            const unsigned short* p = ebq + ct * 16 * SZEB;
            s16x8 B0 = *(const s16x8*)p;
            s16x8 B1 = *(const s16x8*)(p + 32);
            f32x4 acc = {0.f, 0.f, 0.f, 0.f};
            acc = __builtin_amdgcn_mfma_f32_16x16x32_bf16(A0, B0, acc, 0, 0, 0);
            acc = __builtin_amdgcn_mfma_f32_16x16x32_bf16(A1, B1, acc, 0, 0, 0);
            float en = enorm_l[ch * ECH + ct * 16 + n15];
#pragma unroll
            for (int r = 0; r < 4; ++r) {
                float d = fmaf(-2.f, acc[r], en);
                bmin[r] = fminf(bmin[r], d);
            }
        }
    }
#pragma unroll
    for (int off = 1; off < 16; off <<= 1)
#pragma unroll
        for (int r = 0; r < 4; ++r)
            bmin[r] = fminf(bmin[r], __shfl_xor(bmin[r], off));
    if (n15 == 0)
#pragma unroll
        for (int r = 0; r < 4; ++r) dmin_l[w * 16 + 4 * q + r] = bmin[r];
    __syncthreads();

    // ---- pass 2: identical compute, collect candidates within margin.
    //      chunk order 3,0,1,2: chunk 3 is still resident -> no restage ----
    float thr[4];
#pragma unroll
    for (int r = 0; r < 4; ++r) thr[r] = dmin_l[w * 16 + 4 * q + r] + MARGIN;
    for (int cc = 0; cc < 4; ++cc) {
        int ch = (cc == 0) ? 3 : (cc - 1);
        if (cc) {
            __syncthreads();
#pragma unroll
            for (int rep = 0; rep < 8; ++rep) {
                int i = tid + rep * 256;
                int row = i >> 3, j = i & 7;
                ((float4*)&ebl[row * SZEB])[j] =
                    ((const float4*)(eb + (size_t)(ch * ECH + row) * CH))[j];
            }
            __syncthreads();
        }
        for (int ct = 0; ct < 16; ++ct) {
            const unsigned short* p = ebq + ct * 16 * SZEB;
            s16x8 B0 = *(const s16x8*)p;
            s16x8 B1 = *(const s16x8*)(p + 32);
            f32x4 acc = {0.f, 0.f, 0.f, 0.f};
            acc = __builtin_amdgcn_mfma_f32_16x16x32_bf16(A0, B0, acc, 0, 0, 0);
            acc = __builtin_amdgcn_mfma_f32_16x16x32_bf16(A1, B1, acc, 0, 0, 0);
            float en = enorm_l[ch * ECH + ct * 16 + n15];
#pragma unroll
            for (int r = 0; r < 4; ++r) {
                float d = fmaf(-2.f, acc[r], en);
                if (d <= thr[r]) {
                    int t = w * 16 + 4 * q + r;
                    int pos = atomicAdd(&ccnt[t], 1);
                    if (pos < CAP) cand[t][pos] = ch * ECH + ct * 16 + n15;
                }
            }
        }
    }
    __syncthreads();

    // ---- exact fp32 rescore of candidates (frozen arithmetic) ----
    if (tid < MTOK) {
        int t = tid;
        const float* zrow = &zl[t * SZZ];
        int cnt = ccnt[t];
        float best = 3.4e38f;
        int bi = 0;
        if (cnt <= CAP) {
            for (int j = 0; j < cnt; ++j) {
                int c = cand[t][j];
                float d = exact_dist(zrow, emb, enorm_l, c);
                if (d < best || (d == best && c < bi)) { best = d; bi = c; }
            }
        } else {   // overflow fallback (provably ~never): exact scan, ascending
            for (int c = 0; c < KC; ++c) {
                float d = exact_dist(zrow, emb, enorm_l, c);
                if (d < best) { best = d; bi = c; }
            }
        }
        fi[t] = bi;
        out[OFF_IDX + t0 + t] = (float)bi;   // coalesced
        atomicAdd(&hist[bi], 1);
    }
    __syncthreads();

    // ---- z_q epilogue: z + (e[code] - z), coalesced per channel ----
#pragma unroll
    for (int j = 0; j < 16; ++j) {
        int idx = tid + j * 256;   // 0..4095
        int c = idx >> 6;
        int t = idx & 63;
        int code = fi[t];
        float ev = emb[(size_t)code * CH + c];   // L1/L2-hot gather
        float zv = zl[t * SZZ + c];
        out[OFF_ZQ + ((size_t)bb * CH + c) * SP + s0 + t] = zv + (ev - zv);
    }

    // ---- z statistics at kernel tail (atomics off the critical path) ----
    {
        int c = tid >> 2, qq = tid & 3;
        float s1 = 0.f, s2 = 0.f;
        for (int tt = 0; tt < 16; ++tt) {
            float v = zl[(qq * 16 + tt) * SZZ + c];
            s1 += v;
            s2 = fmaf(v, v, s2);
        }
        zs1[tid] = s1;
        zs2[tid] = s2;
    }
    __syncthreads();
    if (tid < 64) {
        float a = zs1[4 * tid] + zs1[4 * tid + 1] + zs1[4 * tid + 2] + zs1[4 * tid + 3];
        atomicAdd(&sum_zc[tid], a);
        float bsum = zs2[4 * tid] + zs2[4 * tid + 1] + zs2[4 * tid + 2] + zs2[4 * tid + 3];
        for (int off = 32; off; off >>= 1) bsum += __shfl_down(bsum, off);
        if (tid == 0) atomicAdd(&sums[0], bsum);
    }
}

__global__ __launch_bounds__(1024) void finalize(const int* __restrict__ hist,
                                                 const float* __restrict__ sums,
                                                 const float* __restrict__ sum_zc,
                                                 const float* __restrict__ sum_ec,
                                                 float* __restrict__ out) {
    __shared__ float red[1024];
    int k = threadIdx.x;
    float p = (float)hist[k] * (1.0f / (float)NTOK);
    red[k] = p * logf(p + 1e-10f);
    __syncthreads();
    for (int off = 512; off; off >>= 1) {
        if (k < off) red[k] += red[k + off];
        __syncthreads();
    }
    if (k == 0) {
        out[OFF_PERP] = expf(-red[0]);
        out[OFF_LOSS] = 0.f;
        double dot = 0.0;
        for (int c = 0; c < CH; ++c) dot += (double)sum_zc[c] * (double)sum_ec[c];
        double mean = ((double)KC * (double)sums[0] + (double)NTOK * (double)sums[1] - 2.0 * dot)
                      / ((double)NTOK * (double)KC);
        out[OFF_MEAN] = (float)mean;
    }
}

extern "C" void kernel_launch(void* const* d_in, const int* in_sizes, int n_in,
                              void* d_out, int out_size, void* d_ws, size_t ws_size,
                              hipStream_t stream) {
    const float* z   = (const float*)d_in[0];
    const float* emb = (const float*)d_in[1];
    float* out = (float*)d_out;

    int*            hist   = (int*)d_ws;
    float*          sums   = (float*)d_ws + 1024;   // [0]=sum_z2 [1]=sum_e2
    float*          sum_zc = (float*)d_ws + 1026;
    float*          sum_ec = (float*)d_ws + 1090;
    float*          enorm  = (float*)d_ws + 1154;
    unsigned short* eb     = (unsigned short*)((int*)d_ws + 4096);  // 128 KB bf16 table

    prep<<<13, 256, 0, stream>>>(emb, hist, sums, sum_zc, sum_ec, enorm, eb);
    vq_main<<<NTOK / MTOK, 256, 0, stream>>>(z, emb, eb, enorm, out, hist, sums, sum_zc);
    finalize<<<1, 1024, 0, stream>>>(hist, sums, sum_zc, sum_ec, out);
}